// Round 1
// baseline (76.536 us; speedup 1.0000x reference)
//
#include <hip/hip_runtime.h>

// out[i][j] = x[i][j] + sum_p log(p) * x[(i - p) mod 8192][j]
// x: (8192, 4096) fp32. Memory-bound streaming stencil along rows.

#define ROWS 8192
#define COLS 4096
#define COLS4 (COLS / 4)   // 1024 float4 per row
#define LOG2_COLS4 10

__global__ __launch_bounds__(256) void spectral_kernel(
    const float4* __restrict__ x, float4* __restrict__ out, int total) {
  int idx = blockIdx.x * blockDim.x + threadIdx.x;
  const int stride = gridDim.x * blockDim.x;
  for (; idx < total; idx += stride) {
    const int i = idx >> LOG2_COLS4;
    const int j = idx & (COLS4 - 1);
    const float4 a = x[idx];
    float4 acc = a;
#define ADDP(P, LP)                                                  \
    {                                                                \
      const int r = (i - (P)) & (ROWS - 1);                          \
      const float4 v = x[(r << LOG2_COLS4) + j];                     \
      acc.x = fmaf((LP), v.x, acc.x);                                \
      acc.y = fmaf((LP), v.y, acc.y);                                \
      acc.z = fmaf((LP), v.z, acc.z);                                \
      acc.w = fmaf((LP), v.w, acc.w);                                \
    }
    ADDP(2,  0.69314718055994530942f)   // ln 2
    ADDP(3,  1.09861228866810969140f)   // ln 3
    ADDP(5,  1.60943791243410037460f)   // ln 5
    ADDP(7,  1.94591014905531330511f)   // ln 7
    ADDP(11, 2.39789527279837054406f)   // ln 11
    ADDP(13, 2.56494935746153673605f)   // ln 13
    ADDP(17, 2.83321334405621608025f)   // ln 17
    ADDP(19, 2.94443897916644046001f)   // ln 19
#undef ADDP
    out[idx] = acc;
  }
}

extern "C" void kernel_launch(void* const* d_in, const int* in_sizes, int n_in,
                              void* d_out, int out_size, void* d_ws, size_t ws_size,
                              hipStream_t stream) {
  const float4* x = (const float4*)d_in[0];
  float4* out = (float4*)d_out;
  const int total = ROWS * COLS4;  // 8M float4 items
  const int block = 256;
  const int grid = 2048;           // 256 CU x 8 blocks, grid-stride covers the rest
  spectral_kernel<<<grid, block, 0, stream>>>(x, out, total);
}

// Round 3
// 63.771 us; speedup vs baseline: 1.2002x; 1.2002x over previous
//
#include <hip/hip_runtime.h>

// out[i][j] = x[i][j] + sum_p ln(p) * x[(i - p) mod 8192][j]
// x: (8192, 4096) fp32. Register-blocked sliding window along rows:
// each thread owns one float4 column slot and R consecutive output rows.
// Loads rows b-19 .. b+R-1 once each; each loaded row feeds up to 9 accs.

#define ROWS 8192
#define COLS 4096
#define COLS4 (COLS / 4)   // 1024 float4 per row
#define LOG2_COLS4 10
#define R 16               // output rows per thread
#define MAXSHIFT 19

typedef float f32x4 __attribute__((ext_vector_type(4)));

// shift 0 (identity, coeff 1) + the 8 primes with ln(p)
__constant__ constexpr int   SHIFT[9] = {0, 2, 3, 5, 7, 11, 13, 17, 19};
__constant__ constexpr float COEF[9]  = {
    1.0f,
    0.69314718055994530942f,  // ln 2
    1.09861228866810969140f,  // ln 3
    1.60943791243410037460f,  // ln 5
    1.94591014905531330511f,  // ln 7
    2.39789527279837054406f,  // ln 11
    2.56494935746153673605f,  // ln 13
    2.83321334405621608025f,  // ln 17
    2.94443897916644046001f   // ln 19
};

__global__ __launch_bounds__(256) void spectral_kernel(
    const f32x4* __restrict__ x, f32x4* __restrict__ out) {
  const int g = blockIdx.x * blockDim.x + threadIdx.x;
  const int j = g & (COLS4 - 1);            // float4 column slot
  const int b = (g >> LOG2_COLS4) * R;      // first output row of this thread

  f32x4 acc[R];
#pragma unroll
  for (int k = 0; k < R; ++k) acc[k] = (f32x4)(0.f);

#pragma unroll
  for (int t = 0; t < R + MAXSHIFT; ++t) {
    const int r = (b - MAXSHIFT + t) & (ROWS - 1);
    const f32x4 v = x[(r << LOG2_COLS4) + j];
#pragma unroll
    for (int s = 0; s < 9; ++s) {
      const int k = t - MAXSHIFT + SHIFT[s];   // output row (rel. to b) fed by v
      if (k >= 0 && k < R) {                   // folds at compile time
        acc[k] = v * COEF[s] + acc[k];
      }
    }
  }

#pragma unroll
  for (int k = 0; k < R; ++k) {
    __builtin_nontemporal_store(acc[k], &out[((b + k) << LOG2_COLS4) + j]);
  }
}

extern "C" void kernel_launch(void* const* d_in, const int* in_sizes, int n_in,
                              void* d_out, int out_size, void* d_ws, size_t ws_size,
                              hipStream_t stream) {
  const f32x4* x = (const f32x4*)d_in[0];
  f32x4* out = (f32x4*)d_out;
  const int total_threads = (ROWS / R) * COLS4;  // 512 * 1024 = 524288
  const int block = 256;
  const int grid = total_threads / block;        // 2048
  spectral_kernel<<<grid, block, 0, stream>>>(x, out);
}

// Round 4
// 52.337 us; speedup vs baseline: 1.4624x; 1.2185x over previous
//
#include <hip/hip_runtime.h>

// out[i][j] = x[i][j] + sum_p ln(p) * x[(i - p) mod 8192][j]
// x: (8192, 4096) fp32. Register-blocked sliding window along rows:
// each thread owns one float4 column slot and R=32 consecutive output rows.
// Loads rows b-19 .. b+R-1 once each (51 loads -> 32 outputs, 1.59x).
// XCD-contiguous stripe swizzle: each XCD owns 32 consecutive stripes so
// the 19-row halo shared by adjacent stripes stays in that XCD's L2.

#define ROWS 8192
#define COLS 4096
#define COLS4 (COLS / 4)   // 1024 float4 per row
#define LOG2_COLS4 10
#define R 32               // output rows per thread
#define MAXSHIFT 19
#define NXCD 8

typedef float f32x4 __attribute__((ext_vector_type(4)));

// shift 0 (identity, coeff 1) + the 8 primes with ln(p)
__constant__ constexpr int   SHIFT[9] = {0, 2, 3, 5, 7, 11, 13, 17, 19};
__constant__ constexpr float COEF[9]  = {
    1.0f,
    0.69314718055994530942f,  // ln 2
    1.09861228866810969140f,  // ln 3
    1.60943791243410037460f,  // ln 5
    1.94591014905531330511f,  // ln 7
    2.39789527279837054406f,  // ln 11
    2.56494935746153673605f,  // ln 13
    2.83321334405621608025f,  // ln 17
    2.94443897916644046001f   // ln 19
};

__global__ __launch_bounds__(256) void spectral_kernel(
    const f32x4* __restrict__ x, f32x4* __restrict__ out) {
  // 1024 blocks. Bijective XCD swizzle (1024 % 8 == 0):
  // XCD k gets sblk k*128 .. k*128+127 -> stripes k*32 .. k*32+31 contiguous.
  const int sblk = (blockIdx.x & (NXCD - 1)) * (1024 / NXCD) + (blockIdx.x >> 3);
  const int g = sblk * blockDim.x + threadIdx.x;   // swizzled global thread id
  const int j = g & (COLS4 - 1);                   // float4 column slot
  const int b = (g >> LOG2_COLS4) * R;             // first output row

  f32x4 acc[R];
#pragma unroll
  for (int k = 0; k < R; ++k) acc[k] = (f32x4)(0.f);

#pragma unroll
  for (int t = 0; t < R + MAXSHIFT; ++t) {
    const int r = (b - MAXSHIFT + t) & (ROWS - 1);
    const f32x4 v = x[(r << LOG2_COLS4) + j];
#pragma unroll
    for (int s = 0; s < 9; ++s) {
      const int k = t - MAXSHIFT + SHIFT[s];   // output row (rel. to b) fed by v
      if (k >= 0 && k < R) {                   // folds at compile time
        acc[k] = v * COEF[s] + acc[k];
      }
    }
  }

#pragma unroll
  for (int k = 0; k < R; ++k) {
    __builtin_nontemporal_store(acc[k], &out[((b + k) << LOG2_COLS4) + j]);
  }
}

extern "C" void kernel_launch(void* const* d_in, const int* in_sizes, int n_in,
                              void* d_out, int out_size, void* d_ws, size_t ws_size,
                              hipStream_t stream) {
  const f32x4* x = (const f32x4*)d_in[0];
  f32x4* out = (f32x4*)d_out;
  const int total_threads = (ROWS / R) * COLS4;  // 256 * 1024 = 262144
  const int block = 256;
  const int grid = total_threads / block;        // 1024
  spectral_kernel<<<grid, block, 0, stream>>>(x, out);
}

// Round 5
// 43.154 us; speedup vs baseline: 1.7736x; 1.2128x over previous
//
#include <hip/hip_runtime.h>

// out[i][j] = x[i][j] + sum_p ln(p) * x[(i - p) mod 8192][j]
// x: (8192, 4096) fp32. Rolling-retirement sliding window, f32x2 lanes:
// each thread owns one f32x2 column slot and R=16 consecutive output rows.
// acc[i] is complete at t = i+19 (shift-0 last) -> store immediately, so
// only ~20 accumulators (40 VGPR) are ever live. __launch_bounds__(256,8)
// targets <=64 VGPR -> 8 waves/SIMD for latency hiding.

#define ROWS 8192
#define COLS 4096
#define COLS2 (COLS / 2)   // 2048 f32x2 per row
#define LOG2_COLS2 11
#define R 16               // output rows per thread
#define MAXSHIFT 19
#define NXCD 8

typedef float f32x2 __attribute__((ext_vector_type(2)));

__constant__ constexpr int   SHIFT[9] = {0, 2, 3, 5, 7, 11, 13, 17, 19};
__constant__ constexpr float COEF[9]  = {
    1.0f,
    0.69314718055994530942f,  // ln 2
    1.09861228866810969140f,  // ln 3
    1.60943791243410037460f,  // ln 5
    1.94591014905531330511f,  // ln 7
    2.39789527279837054406f,  // ln 11
    2.56494935746153673605f,  // ln 13
    2.83321334405621608025f,  // ln 17
    2.94443897916644046001f   // ln 19
};

__global__ __launch_bounds__(256, 8) void spectral_kernel(
    const f32x2* __restrict__ x, f32x2* __restrict__ out) {
  // 4096 blocks; bijective XCD-contiguous swizzle (4096 % 8 == 0):
  // XCD k owns blocks k*512..k*512+511 -> contiguous rows, halo stays in L2.
  const int sblk = (blockIdx.x & (NXCD - 1)) * (4096 / NXCD) + (blockIdx.x >> 3);
  const int g = sblk * blockDim.x + threadIdx.x;
  const int j = g & (COLS2 - 1);            // f32x2 column slot
  const int b = (g >> LOG2_COLS2) * R;      // first output row of this thread

  f32x2 acc[R];
#pragma unroll
  for (int k = 0; k < R; ++k) acc[k] = (f32x2)(0.f);

#pragma unroll
  for (int t = 0; t < R + MAXSHIFT; ++t) {
    const int r = (b - MAXSHIFT + t) & (ROWS - 1);
    const f32x2 v = x[(r << LOG2_COLS2) + j];
#pragma unroll
    for (int s = 0; s < 9; ++s) {
      const int k = t - MAXSHIFT + SHIFT[s];   // output row (rel. to b) fed by v
      if (k >= 0 && k < R) {                   // folds at compile time
        acc[k] = v * COEF[s] + acc[k];
      }
    }
    // Rolling retirement: acc[t-MAXSHIFT] just received its final (shift-0)
    // contribution -> store now, freeing its registers.
    if (t >= MAXSHIFT) {
      const int k = t - MAXSHIFT;
      __builtin_nontemporal_store(acc[k], &out[((b + k) << LOG2_COLS2) + j]);
    }
  }
}

extern "C" void kernel_launch(void* const* d_in, const int* in_sizes, int n_in,
                              void* d_out, int out_size, void* d_ws, size_t ws_size,
                              hipStream_t stream) {
  const f32x2* x = (const f32x2*)d_in[0];
  f32x2* out = (f32x2*)d_out;
  const int total_threads = (ROWS / R) * COLS2;  // 512 * 2048 = 1048576
  const int block = 256;
  const int grid = total_threads / block;        // 4096
  spectral_kernel<<<grid, block, 0, stream>>>(x, out);
}